// Round 5
// baseline (497.953 us; speedup 1.0000x reference)
//
#include <hip/hip_runtime.h>
#include <hip/hip_bf16.h>
#include <cmath>
#include <cstdint>
#include <cstddef>

#define DEV __device__ __forceinline__

typedef __attribute__((ext_vector_type(4))) float f32x4;
typedef __attribute__((ext_vector_type(8))) short bf16x8;
typedef __attribute__((ext_vector_type(4))) unsigned int u32x4;
typedef __attribute__((ext_vector_type(4))) unsigned short u16x4;

constexpr int NBATCH = 32;
constexpr int SEQ    = 197;
constexpr int CH     = 768;
constexpr int H3     = 3 * CH;      // 2304
constexpr int NHEADS = 12;
constexpr int HD     = 64;
constexpr int HID    = 3072;
constexpr int TOK    = NBATCH * SEQ;  // 6304
constexpr int TOKP   = 6400;          // padded to 50*128
constexpr int KSPLIT = 3;             // cheby2 split over the 3 power planes
constexpr float LNEPS = 1e-5f;

DEV unsigned short f2bf(float f) {
  unsigned int u = __builtin_bit_cast(unsigned int, f);
  u += 0x7fffu + ((u >> 16) & 1u);   // RNE
  return (unsigned short)(u >> 16);
}
DEV float bf2f(unsigned short s) {
  unsigned int u = ((unsigned int)s) << 16;
  return __builtin_bit_cast(float, u);
}

// fast tanh: tanh(x) = 1 - 2/(e^{2x}+1); v_exp + v_rcp (~4 ops vs ~25 for tanhf)
DEV float fast_tanh(float x) {
  const float e = __expf(2.f * x);
  return 1.f - 2.f * __builtin_amdgcn_rcpf(e + 1.f);
}

// async global->LDS, 16B per lane; lds must be wave-uniform base, HW adds lane*16
DEV void async_copy16(void* lds, const void* gmem) {
  __builtin_amdgcn_global_load_lds(
      (const __attribute__((address_space(1))) unsigned int*)gmem,
      (__attribute__((address_space(3))) unsigned int*)lds, 16, 0, 0);
}

// bijective XCD-aware swizzle (m204): each of the 8 XCDs gets a contiguous
// chunk of the flat (x,y) grid -> neighbor tiles share B-panels in one L2.
DEV void xcd_swizzle(int& bx, int& by) {
  const int gx = (int)gridDim.x;
  const int nwg = gx * (int)gridDim.y;
  const int flat = bx + by * gx;
  const int q = nwg >> 3, r = nwg & 7;
  const int xcd = flat & 7, idx = flat >> 3;
  const int swz = (xcd < r) ? (xcd * (q + 1) + idx)
                            : (r * (q + 1) + (xcd - r) * q + idx);
  bx = swz % gx;
  by = swz / gx;
}

// ---------------- LayerNorm (one wave per row), bf16 out ----------------------------
// POW3=0: plain LN -> [row][CH]. POW3=1: t=tanh(LN), writes [t|t^2|t^3] -> [row][3*CH].
template <int POW3>
__global__ void ln_kernel(const float* __restrict__ xin, const float* __restrict__ gg,
                          const float* __restrict__ bb, unsigned short* __restrict__ outp) {
  const int row  = blockIdx.x * 4 + (threadIdx.x >> 6);
  const int lane = threadIdx.x & 63;
  const int ld   = POW3 ? 3 * CH : CH;
  if (row >= TOK) {           // pad rows -> zeros (row < TOKP by grid)
    u16x4 z = {0, 0, 0, 0};
    #pragma unroll
    for (int c = 0; c < 3; ++c) {
      if (POW3) {
        #pragma unroll
        for (int p = 0; p < 3; ++p)
          *(u16x4*)&outp[(size_t)row * ld + p * CH + c * 256 + lane * 4] = z;
      } else {
        *(u16x4*)&outp[(size_t)row * ld + c * 256 + lane * 4] = z;
      }
    }
    return;
  }
  f32x4 v[3];
  float s = 0.f, s2 = 0.f;
  #pragma unroll
  for (int c = 0; c < 3; ++c) {
    v[c] = *(const f32x4*)&xin[(size_t)row * CH + c * 256 + lane * 4];
    #pragma unroll
    for (int e = 0; e < 4; ++e) { s += v[c][e]; s2 += v[c][e] * v[c][e]; }
  }
  #pragma unroll
  for (int off = 32; off; off >>= 1) { s += __shfl_xor(s, off); s2 += __shfl_xor(s2, off); }
  const float mean = s * (1.f / CH);
  const float var  = s2 * (1.f / CH) - mean * mean;
  const float rs   = rsqrtf(var + LNEPS);
  #pragma unroll
  for (int c = 0; c < 3; ++c) {
    f32x4 gv = *(const f32x4*)&gg[c * 256 + lane * 4];
    f32x4 bv = *(const f32x4*)&bb[c * 256 + lane * 4];
    u16x4 o1, o2, o3;
    #pragma unroll
    for (int e = 0; e < 4; ++e) {
      float f = (v[c][e] - mean) * rs * gv[e] + bv[e];
      if (POW3) {
        f = fast_tanh(f);
        const float f2 = f * f, f3 = f2 * f;
        o1[e] = f2bf(f); o2[e] = f2bf(f2); o3[e] = f2bf(f3);
      } else {
        o1[e] = f2bf(f);
      }
    }
    if (POW3) {
      *(u16x4*)&outp[(size_t)row * ld + c * 256 + lane * 4]           = o1;
      *(u16x4*)&outp[(size_t)row * ld + CH + c * 256 + lane * 4]      = o2;
      *(u16x4*)&outp[(size_t)row * ld + 2 * CH + c * 256 + lane * 4]  = o3;
    } else {
      *(u16x4*)&outp[(size_t)row * ld + c * 256 + lane * 4] = o1;
    }
  }
}

// ---------------- transpose fp32 (K x N) -> bf16 (N x K) ----------------------------
__global__ void transpose_bf16(const float* __restrict__ in, unsigned short* __restrict__ outp,
                               int K, int N) {
  __shared__ unsigned short tile[64][65];
  const int k0 = blockIdx.x * 64, n0 = blockIdx.y * 64;
  const int tc = threadIdx.x & 63, tr = threadIdx.x >> 6;
  #pragma unroll
  for (int rr = 0; rr < 64; rr += 4)
    tile[rr + tr][tc] = f2bf(in[(size_t)(k0 + rr + tr) * N + n0 + tc]);
  __syncthreads();
  #pragma unroll
  for (int rr = 0; rr < 64; rr += 4)
    outp[(size_t)(n0 + rr + tr) * K + k0 + tc] = tile[tc][rr + tr];
}

// -------- fold cheby coeffs (I,O,4) -> monomial weights, bf16 -----------------------
// W1 = c[...,1]-3c[...,3], W2 = 2c[...,2], W3 = 4c[...,3]
// PSPLIT=0: B^T row layout [O][3I] = [W1|W2|W3]  (cheby1, A = [t|t^2|t^3])
// PSPLIT=1: power-major planes [3][O][I]          (cheby2, A planes u^p)
// Also emits per-(i-block) partial bias rows: partial[iblk][o] = sum_{i in blk}(c0 - c2)
template <int PSPLIT>
__global__ void cheb_combine(const float* __restrict__ cc, unsigned short* __restrict__ outp,
                             float* __restrict__ partial, int I, int O) {
  __shared__ unsigned short t1[64][65];
  __shared__ unsigned short t2[64][65];
  __shared__ unsigned short t3[64][65];
  __shared__ float psum[4][64];
  const int i0 = blockIdx.x * 64, o0 = blockIdx.y * 64;
  const int tc = threadIdx.x & 63, tr = threadIdx.x >> 6;
  float bs = 0.f;
  #pragma unroll
  for (int rr = 0; rr < 64; rr += 4) {
    f32x4 v = *(const f32x4*)&cc[((size_t)(i0 + rr + tr) * O + (o0 + tc)) * 4];
    t1[rr + tr][tc] = f2bf(v[1] - 3.f * v[3]);
    t2[rr + tr][tc] = f2bf(2.f * v[2]);
    t3[rr + tr][tc] = f2bf(4.f * v[3]);
    bs += v[0] - v[2];
  }
  psum[tr][tc] = bs;
  __syncthreads();
  #pragma unroll
  for (int rr = 0; rr < 64; rr += 4) {
    if (PSPLIT == 0) {
      const size_t K3 = (size_t)3 * I;
      size_t ob = (size_t)(o0 + rr + tr) * K3 + i0 + tc;
      outp[ob]         = t1[tc][rr + tr];
      outp[ob + I]     = t2[tc][rr + tr];
      outp[ob + 2 * I] = t3[tc][rr + tr];
    } else {
      const size_t plane = (size_t)O * I;
      size_t ob = (size_t)(o0 + rr + tr) * I + i0 + tc;
      outp[ob]             = t1[tc][rr + tr];
      outp[ob + plane]     = t2[tc][rr + tr];
      outp[ob + 2 * plane] = t3[tc][rr + tr];
    }
  }
  if (tr == 0)
    partial[(size_t)blockIdx.x * O + o0 + tc] =
        psum[0][tc] + psum[1][tc] + psum[2][tc] + psum[3][tc];
}

// deterministic finish: bias[o] = sum_k partial[k][o]
__global__ void bias_finish(const float* __restrict__ partial, float* __restrict__ bias,
                            int nblk, int O) {
  const int o = blockIdx.x * 256 + threadIdx.x;
  float s = 0.f;
  for (int k = 0; k < nblk; ++k) s += partial[(size_t)k * O + o];
  bias[o] = s;
}

__global__ void zero_pad_rows(unsigned short* __restrict__ p) {
  const size_t idx = ((size_t)blockIdx.x * 256 + threadIdx.x) * 4;
  u16x4 z = {0, 0, 0, 0};
  *(u16x4*)&p[(size_t)TOK * CH + idx] = z;
}

// ---------------- 128x128x32 bf16 MFMA GEMM, 1-ahead prefetch pipeline --------------
// A bf16 [rows][Ktot] row-major; BT bf16 [Nn][Ktot]. 256 thr, 2x2 waves. XCD-swizzled.
// EPI: 0 -> bf16 C[row][Nn]
//      1 -> fp32 acc+bias+resid (0 on pad rows)
//      2 -> u=fast_tanh(acc+bias); bf16 power-major planes [3][TOKP][Nn]: u,u^2,u^3
//      3 -> power-split over blockIdx.z: A += z*TOKP*Ktot, BT += z*Nn*Ktot;
//           fp32 partial -> C[(z*TOKP+row)][Nn]
template <int EPI>
__global__ __launch_bounds__(256)
void gemm_kernel(const unsigned short* __restrict__ A,
                 const unsigned short* __restrict__ BT,
                 const int Ktot, const int Nn,
                 const float* __restrict__ bias,
                 const float* __restrict__ resid,
                 void* __restrict__ Cout) {
  __shared__ __align__(16) unsigned short As[2][128 * 32];
  __shared__ __align__(16) unsigned short Bs[2][128 * 32];
  if (EPI == 3) {
    A  += (size_t)blockIdx.z * TOKP * Ktot;
    BT += (size_t)blockIdx.z * Nn * Ktot;
  }
  int bx = blockIdx.x, by = blockIdx.y;
  xcd_swizzle(bx, by);
  const int t = threadIdx.x;
  const int lane = t & 63;
  const int wid = t >> 6;
  const int wm = wid >> 1, wn = wid & 1;
  const int bm = bx * 128;
  const int bn = by * 128;
  const int srow = t >> 2;          // staging row within 64-row half
  const int scol = (t & 3) * 8;     // staging col (bf16)
  const int nkt = Ktot >> 5;
  f32x4 acc[4][4] = {};

  auto stage = [&](int buf, int kt) {
    const int kk = kt << 5;
    char* lb = (char*)&Bs[buf][0] + (wid << 10);
    async_copy16(lb,        &BT[(size_t)(bn + srow) * Ktot + kk + scol]);
    async_copy16(lb + 4096, &BT[(size_t)(bn + 64 + srow) * Ktot + kk + scol]);
    char* la = (char*)&As[buf][0] + (wid << 10);
    async_copy16(la,        &A[(size_t)(bm + srow) * Ktot + kk + scol]);
    async_copy16(la + 4096, &A[(size_t)(bm + 64 + srow) * Ktot + kk + scol]);
  };

  int cur = 0;
  stage(0, 0);
  for (int kt = 0; kt < nkt; ++kt) {
    if (kt + 1 < nkt) {
      stage(cur ^ 1, kt + 1);                       // issue next tile's loads first
      asm volatile("s_waitcnt vmcnt(4)" ::: "memory");   // cur tile's 4 loads done
    } else {
      asm volatile("s_waitcnt vmcnt(0)" ::: "memory");
    }
    __builtin_amdgcn_s_barrier();                   // cur staged by all waves
    __builtin_amdgcn_sched_barrier(0);
    bf16x8 af[4], bfr[4];
    const int frow = lane & 15;
    const int fk = (lane >> 4) * 8;
    #pragma unroll
    for (int m = 0; m < 4; ++m)
      af[m] = *(const bf16x8*)&As[cur][(wm * 64 + m * 16 + frow) * 32 + fk];
    #pragma unroll
    for (int n = 0; n < 4; ++n)
      bfr[n] = *(const bf16x8*)&Bs[cur][(wn * 64 + n * 16 + frow) * 32 + fk];
    #pragma unroll
    for (int m = 0; m < 4; ++m)
      #pragma unroll
      for (int n = 0; n < 4; ++n)
        acc[m][n] = __builtin_amdgcn_mfma_f32_16x16x32_bf16(af[m], bfr[n], acc[m][n], 0, 0, 0);
    __builtin_amdgcn_s_barrier();                   // reads done before next overwrite
    cur ^= 1;
  }
  // epilogue: C/D frag layout col=lane&15, row=4*(lane>>4)+r  [verified m89]
  #pragma unroll
  for (int m = 0; m < 4; ++m) {
    #pragma unroll
    for (int n = 0; n < 4; ++n) {
      #pragma unroll
      for (int r = 0; r < 4; ++r) {
        const int row = bm + wm * 64 + m * 16 + (lane >> 4) * 4 + r;
        const int col = bn + wn * 64 + n * 16 + (lane & 15);
        const float v = acc[m][n][r];
        if (EPI == 0) {
          ((unsigned short*)Cout)[(size_t)row * Nn + col] = f2bf(v);
        } else if (EPI == 1) {
          float o = 0.f;
          if (row < TOK) o = v + bias[col] + resid[(size_t)row * Nn + col];
          ((float*)Cout)[(size_t)row * Nn + col] = o;
        } else if (EPI == 2) {
          const float u = fast_tanh(v + bias[col]);
          const float u2 = u * u, u3 = u2 * u;
          unsigned short* o = (unsigned short*)Cout;
          const size_t plane = (size_t)TOKP * Nn;
          const size_t b0 = (size_t)row * Nn + col;
          o[b0]             = f2bf(u);
          o[b0 + plane]     = f2bf(u2);
          o[b0 + 2 * plane] = f2bf(u3);
        } else {
          ((float*)Cout)[((size_t)blockIdx.z * TOKP + row) * Nn + col] = v;
        }
      }
    }
  }
}

// split-K finish for cheby2: out = sum_z part + bias + resid (rows < TOK)
__global__ void cheb2_reduce(const float* __restrict__ part, const float* __restrict__ bias,
                             const float* __restrict__ resid, float* __restrict__ outp) {
  const size_t idx = ((size_t)blockIdx.x * 256 + threadIdx.x) * 4;
  const int col = (int)(idx % CH);
  f32x4 s = *(const f32x4*)&part[idx];
  #pragma unroll
  for (int z = 1; z < KSPLIT; ++z) {
    f32x4 p = *(const f32x4*)&part[(size_t)z * TOKP * CH + idx];
    #pragma unroll
    for (int e = 0; e < 4; ++e) s[e] += p[e];
  }
  const f32x4 bv = *(const f32x4*)&bias[col];
  const f32x4 rv = *(const f32x4*)&resid[idx];
  f32x4 o;
  #pragma unroll
  for (int e = 0; e < 4; ++e) o[e] = s[e] + bv[e] + rv[e];
  *(f32x4*)&outp[idx] = o;
}

// ---------------- attention: one block per (b,head), 4 waves ------------------------
__global__ __launch_bounds__(256)
void attn_kernel(const unsigned short* __restrict__ qkv, unsigned short* __restrict__ aout) {
  constexpr int VSTR = 232;   // padded col stride (keys), 464B rows: ~2-way banks, 16B aligned
  __shared__ __align__(16) unsigned short Vlds[64 * VSTR];      // V^T [d][key]
  __shared__ __align__(16) unsigned short Plds[4][16 * VSTR];   // per-wave P [q][key]
  const int bh = blockIdx.x;
  const int b = bh / NHEADS, hh = bh - b * NHEADS;
  const int t = threadIdx.x, lane = t & 63, wid = t >> 6;
  const size_t base = (size_t)b * SEQ * H3;
  // stage V^T (zero pad keys >= SEQ)
  const int part = t & 7, key0 = t >> 3;
  for (int it = 0; it < 7; ++it) {
    const int key = key0 + it * 32;
    u32x4 raw = {0, 0, 0, 0};
    if (key < SEQ)
      raw = *(const u32x4*)&qkv[base + (size_t)key * H3 + 2 * CH + hh * HD + part * 8];
    const unsigned short* us = (const unsigned short*)&raw;
    #pragma unroll
    for (int e = 0; e < 8; ++e)
      Vlds[(part * 8 + e) * VSTR + key] = us[e];
  }
  // zero P pad columns [208,224)
  for (int idx = t; idx < 4 * 16 * 16; idx += 256) {
    const int buf = idx >> 8, rr = (idx >> 4) & 15, ccc = idx & 15;
    Plds[buf][rr * VSTR + 208 + ccc] = 0;
  }
  __syncthreads();

  for (int qt = wid; qt < 13; qt += 4) {
    const int qrow = qt * 16 + (lane & 15);              // may be >=SEQ; stores guarded
    const size_t qbase = base + (size_t)qrow * H3 + hh * HD + (lane >> 4) * 8;
    const bf16x8 qf0 = *(const bf16x8*)&qkv[qbase];
    const bf16x8 qf1 = *(const bf16x8*)&qkv[qbase + 32];
    float sv[13][4];
    #pragma unroll
    for (int ktile = 0; ktile < 13; ++ktile) {
      const int keyc = ktile * 16 + (lane & 15);
      const size_t kbase = base + (size_t)keyc * H3 + CH + hh * HD + (lane >> 4) * 8;
      const bf16x8 kf0 = *(const bf16x8*)&qkv[kbase];
      const bf16x8 kf1 = *(const bf16x8*)&qkv[kbase + 32];
      f32x4 s = {0.f, 0.f, 0.f, 0.f};
      s = __builtin_amdgcn_mfma_f32_16x16x32_bf16(qf0, kf0, s, 0, 0, 0);
      s = __builtin_amdgcn_mfma_f32_16x16x32_bf16(qf1, kf1, s, 0, 0, 0);
      const bool valid = keyc < SEQ;
      #pragma unroll
      for (int r = 0; r < 4; ++r)
        sv[ktile][r] = valid ? s[r] * 0.125f : -INFINITY;
    }
    // softmax over keys: rows live across the 16 lanes of each quarter-wave
    float rsum[4];
    #pragma unroll
    for (int r = 0; r < 4; ++r) {
      float mx = -INFINITY;
      #pragma unroll
      for (int kt2 = 0; kt2 < 13; ++kt2) mx = fmaxf(mx, sv[kt2][r]);
      #pragma unroll
      for (int off = 1; off < 16; off <<= 1) mx = fmaxf(mx, __shfl_xor(mx, off));
      float sum = 0.f;
      #pragma unroll
      for (int kt2 = 0; kt2 < 13; ++kt2) {
        const float p = __expf(sv[kt2][r] - mx);
        sv[kt2][r] = p;
        sum += p;
      }
      #pragma unroll
      for (int off = 1; off < 16; off <<= 1) sum += __shfl_xor(sum, off);
      rsum[r] = sum;
    }
    // P -> LDS (transpose lanes->rows for the PV A-operand)
    const int g4 = (lane >> 4) * 4;
    #pragma unroll
    for (int kt2 = 0; kt2 < 13; ++kt2)
      #pragma unroll
      for (int r = 0; r < 4; ++r)
        Plds[wid][(g4 + r) * VSTR + kt2 * 16 + (lane & 15)] = f2bf(sv[kt2][r]);
    asm volatile("s_waitcnt lgkmcnt(0)" ::: "memory");   // same-wave ds_write -> ds_read
    // O = P @ V
    f32x4 oacc[4] = {};
    #pragma unroll
    for (int ks = 0; ks < 7; ++ks) {
      const bf16x8 pf = *(const bf16x8*)&Plds[wid][(lane & 15) * VSTR + ks * 32 + (lane >> 4) * 8];
      #pragma unroll
      for (int n = 0; n < 4; ++n) {
        const bf16x8 vf = *(const bf16x8*)&Vlds[(n * 16 + (lane & 15)) * VSTR + ks * 32 + (lane >> 4) * 8];
        oacc[n] = __builtin_amdgcn_mfma_f32_16x16x32_bf16(pf, vf, oacc[n], 0, 0, 0);
      }
    }
    #pragma unroll
    for (int n = 0; n < 4; ++n)
      #pragma unroll
      for (int r = 0; r < 4; ++r) {
        const int q = qt * 16 + g4 + r;
        if (q < SEQ) {
          const float val = oacc[n][r] / rsum[r];
          aout[(size_t)(b * SEQ + q) * CH + hh * HD + n * 16 + (lane & 15)] = f2bf(val);
        }
      }
  }
}

extern "C" void kernel_launch(void* const* d_in, const int* in_sizes, int n_in,
                              void* d_out, int out_size, void* d_ws, size_t ws_size,
                              hipStream_t stream) {
  const float* x      = (const float*)d_in[0];
  const float* g1     = (const float*)d_in[1];
  const float* b1     = (const float*)d_in[2];
  const float* w_qkv  = (const float*)d_in[3];
  const float* w_proj = (const float*)d_in[4];
  const float* b_proj = (const float*)d_in[5];
  const float* g2     = (const float*)d_in[6];
  const float* b2     = (const float*)d_in[7];
  const float* c1     = (const float*)d_in[8];
  const float* c2     = (const float*)d_in[9];

  // ---- workspace layout with lifetime-based aliasing (peak ~211 MB) ----
  // unionA: phase-1 buffers {h, wqkvT, qkvb, aoutb, wprojT} all dead before cheby1
  //         writes ub (118 MB power-major planes) over them.
  // unionB: {c1T, t1b3} dead after cheby1; partK (59 MB) aliases them.
  char* ws = (char*)d_ws;
  const size_t SZ_H      = (size_t)TOKP * CH * 2;        //  9,830,400
  const size_t SZ_WQKVT  = (size_t)H3 * CH * 2;          //  3,538,944
  const size_t SZ_QKVB   = (size_t)TOKP * H3 * 2;        // 29,491,200
  const size_t SZ_AOUTB  = (size_t)TOKP * CH * 2;        //  9,830,400
  const size_t SZ_WPROJT = (size_t)CH * CH * 2;          //  1,179,648
  const size_t SZ_UB     = (size_t)3 * TOKP * HID * 2;   // 117,964,800
  const size_t SZ_C1T    = (size_t)HID * 3 * CH * 2;     // 14,155,776
  const size_t SZ_T1B3   = (size_t)TOKP * 3 * CH * 2;    // 29,491,200
  const size_t SZ_PARTK  = (size_t)KSPLIT * TOKP * CH * 4; // 58,982,400
  const size_t SZ_C2T    = (size_t)3 * CH * HID * 2;     // 14,155,776
  const size_t SZ_XMID   = (size_t)TOKP * CH * 4;        // 19,660,800

  size_t off = 0;
  const size_t unionA = off;                 // h | wqkvT | qkvb | aoutb | wprojT  OR  ub
  {
    size_t phase1 = SZ_H + SZ_WQKVT + SZ_QKVB + SZ_AOUTB + SZ_WPROJT;  // 53.9 MB
    off += (SZ_UB > phase1 ? SZ_UB : phase1);
  }
  const size_t unionB = off;                 // c1T + t1b3  OR  partK
  {
    size_t ab = SZ_C1T + SZ_T1B3;            // 43.6 MB
    off += (SZ_PARTK > ab ? SZ_PARTK : ab);
  }
  const size_t o_c2T  = off; off += SZ_C2T;
  const size_t o_xmid = off; off += SZ_XMID;
  const size_t o_b1   = off; off += (size_t)HID * 4;
  const size_t o_b2   = off; off += (size_t)CH * 4;
  const size_t o_p1   = off; off += (size_t)(CH / 64) * HID * 4;
  const size_t o_p2   = off; off += (size_t)(HID / 64) * CH * 4;

  unsigned short* h      = (unsigned short*)(ws + unionA);
  unsigned short* wqkvT  = (unsigned short*)(ws + unionA + SZ_H);
  unsigned short* qkvb   = (unsigned short*)(ws + unionA + SZ_H + SZ_WQKVT);
  unsigned short* aoutb  = (unsigned short*)(ws + unionA + SZ_H + SZ_WQKVT + SZ_QKVB);
  unsigned short* wprojT = (unsigned short*)(ws + unionA + SZ_H + SZ_WQKVT + SZ_QKVB + SZ_AOUTB);
  unsigned short* ub     = (unsigned short*)(ws + unionA);   // [3][TOKP][HID]
  unsigned short* c1T    = (unsigned short*)(ws + unionB);
  unsigned short* t1b3   = (unsigned short*)(ws + unionB + SZ_C1T);
  float*          partK  = (float*)(ws + unionB);
  unsigned short* c2T    = (unsigned short*)(ws + o_c2T);    // [3][CH][HID]
  float*          xmid   = (float*)(ws + o_xmid);
  float*          bias1  = (float*)(ws + o_b1);
  float*          bias2  = (float*)(ws + o_b2);
  float*          part1  = (float*)(ws + o_p1);
  float*          part2  = (float*)(ws + o_p2);
  (void)ws_size; (void)in_sizes; (void)n_in; (void)out_size;

  // ---- per-launch weight prep (bf16, pre-transposed / cheby-folded) ----
  transpose_bf16<<<dim3(CH / 64, H3 / 64), 256, 0, stream>>>(w_qkv, wqkvT, CH, H3);
  transpose_bf16<<<dim3(CH / 64, CH / 64), 256, 0, stream>>>(w_proj, wprojT, CH, CH);
  cheb_combine<0><<<dim3(CH / 64, HID / 64), 256, 0, stream>>>(c1, c1T, part1, CH, HID);
  cheb_combine<1><<<dim3(HID / 64, CH / 64), 256, 0, stream>>>(c2, c2T, part2, HID, CH);
  bias_finish<<<dim3(HID / 256), 256, 0, stream>>>(part1, bias1, CH / 64, HID);
  bias_finish<<<dim3(CH / 256), 256, 0, stream>>>(part2, bias2, HID / 64, CH);
  zero_pad_rows<<<dim3(72), 256, 0, stream>>>(aoutb);

  // ---- main pipeline ----
  ln_kernel<0><<<dim3(TOKP / 4), 256, 0, stream>>>(x, g1, b1, h);
  gemm_kernel<0><<<dim3(TOKP / 128, H3 / 128), 256, 0, stream>>>(h, wqkvT, CH, H3,
                                                                 nullptr, nullptr, qkvb);
  attn_kernel<<<dim3(NBATCH * NHEADS), 256, 0, stream>>>(qkvb, aoutb);
  gemm_kernel<1><<<dim3(TOKP / 128, CH / 128), 256, 0, stream>>>(aoutb, wprojT, CH, CH,
                                                                 b_proj, x, xmid);
  ln_kernel<1><<<dim3(TOKP / 4), 256, 0, stream>>>(xmid, g2, b2, t1b3);
  // cheby1: plain GEMM, K = 3*CH = 2304; epilogue writes power-major u,u^2,u^3 planes
  gemm_kernel<2><<<dim3(TOKP / 128, HID / 128), 256, 0, stream>>>(t1b3, c1T, H3, HID,
                                                                  bias1, nullptr, ub);
  // cheby2: split over the 3 power planes; per z a plain GEMM with K = HID = 3072
  gemm_kernel<3><<<dim3(TOKP / 128, CH / 128, KSPLIT), 256, 0, stream>>>(ub, c2T, HID, CH,
                                                                         nullptr, nullptr, partK);
  cheb2_reduce<<<dim3(TOK * CH / 1024), 256, 0, stream>>>(partK, bias2, xmid, (float*)d_out);
}

// Round 6
// 412.041 us; speedup vs baseline: 1.2085x; 1.2085x over previous
//
#include <hip/hip_runtime.h>
#include <hip/hip_bf16.h>
#include <cmath>
#include <cstdint>
#include <cstddef>

#define DEV __device__ __forceinline__

typedef __attribute__((ext_vector_type(4))) float f32x4;
typedef __attribute__((ext_vector_type(8))) short bf16x8;
typedef __attribute__((ext_vector_type(4))) unsigned int u32x4;
typedef __attribute__((ext_vector_type(4))) unsigned short u16x4;

constexpr int NBATCH = 32;
constexpr int SEQ    = 197;
constexpr int CH     = 768;
constexpr int H3     = 3 * CH;      // 2304
constexpr int NHEADS = 12;
constexpr int HD     = 64;
constexpr int HID    = 3072;
constexpr int TOK    = NBATCH * SEQ;  // 6304
constexpr int TOKP   = 6400;          // padded to 50*128
constexpr float LNEPS = 1e-5f;

DEV unsigned short f2bf(float f) {
  unsigned int u = __builtin_bit_cast(unsigned int, f);
  u += 0x7fffu + ((u >> 16) & 1u);   // RNE
  return (unsigned short)(u >> 16);
}
DEV float bf2f(unsigned short s) {
  unsigned int u = ((unsigned int)s) << 16;
  return __builtin_bit_cast(float, u);
}

// fast tanh: tanh(x) = 1 - 2/(e^{2x}+1); saturates correctly at +-1
DEV float fast_tanh(float x) {
  const float e = __expf(2.f * x);
  return 1.f - 2.f * __builtin_amdgcn_rcpf(e + 1.f);
}

// async global->LDS, 16B per lane; lds must be wave-uniform base, HW adds lane*16
DEV void async_copy16(void* lds, const void* gmem) {
  __builtin_amdgcn_global_load_lds(
      (const __attribute__((address_space(1))) unsigned int*)gmem,
      (__attribute__((address_space(3))) unsigned int*)lds, 16, 0, 0);
}

// ---------------- LayerNorm (one wave per row), optional tanh, bf16 out -------------
template <int DO_TANH>
__global__ void ln_kernel(const float* __restrict__ xin, const float* __restrict__ gg,
                          const float* __restrict__ bb, unsigned short* __restrict__ outp) {
  const int row  = blockIdx.x * 4 + (threadIdx.x >> 6);
  const int lane = threadIdx.x & 63;
  if (row >= TOK) {           // pad rows -> zeros (row < TOKP by grid)
    u16x4 z = {0, 0, 0, 0};
    #pragma unroll
    for (int c = 0; c < 3; ++c)
      *(u16x4*)&outp[(size_t)row * CH + c * 256 + lane * 4] = z;
    return;
  }
  f32x4 v[3];
  float s = 0.f, s2 = 0.f;
  #pragma unroll
  for (int c = 0; c < 3; ++c) {
    v[c] = *(const f32x4*)&xin[(size_t)row * CH + c * 256 + lane * 4];
    #pragma unroll
    for (int e = 0; e < 4; ++e) { s += v[c][e]; s2 += v[c][e] * v[c][e]; }
  }
  #pragma unroll
  for (int off = 32; off; off >>= 1) { s += __shfl_xor(s, off); s2 += __shfl_xor(s2, off); }
  const float mean = s * (1.f / CH);
  const float var  = s2 * (1.f / CH) - mean * mean;
  const float rs   = rsqrtf(var + LNEPS);
  #pragma unroll
  for (int c = 0; c < 3; ++c) {
    f32x4 gv = *(const f32x4*)&gg[c * 256 + lane * 4];
    f32x4 bv = *(const f32x4*)&bb[c * 256 + lane * 4];
    u16x4 o;
    #pragma unroll
    for (int e = 0; e < 4; ++e) {
      float f = (v[c][e] - mean) * rs * gv[e] + bv[e];
      if (DO_TANH) f = fast_tanh(f);
      o[e] = f2bf(f);
    }
    *(u16x4*)&outp[(size_t)row * CH + c * 256 + lane * 4] = o;
  }
}

// ---------------- transpose fp32 (K x N) -> bf16 (N x K) ----------------------------
__global__ void transpose_bf16(const float* __restrict__ in, unsigned short* __restrict__ outp,
                               int K, int N) {
  __shared__ unsigned short tile[64][65];
  const int k0 = blockIdx.x * 64, n0 = blockIdx.y * 64;
  const int tc = threadIdx.x & 63, tr = threadIdx.x >> 6;
  #pragma unroll
  for (int rr = 0; rr < 64; rr += 4)
    tile[rr + tr][tc] = f2bf(in[(size_t)(k0 + rr + tr) * N + n0 + tc]);
  __syncthreads();
  #pragma unroll
  for (int rr = 0; rr < 64; rr += 4)
    outp[(size_t)(n0 + rr + tr) * K + k0 + tc] = tile[tc][rr + tr];
}

// -------- fold cheby coeffs (I,O,4) -> monomial weight planes bf16 [3][O][I] --------
// W1 = c[...,1]-3c[...,3], W2 = 2c[...,2], W3 = 4c[...,3]
// Also emits per-(i-block) partial bias rows: partial[iblk][o] = sum_{i in blk}(c0 - c2)
__global__ void cheb_combine(const float* __restrict__ cc, unsigned short* __restrict__ outp,
                             float* __restrict__ partial, int I, int O) {
  __shared__ unsigned short t1[64][65];
  __shared__ unsigned short t2[64][65];
  __shared__ unsigned short t3[64][65];
  __shared__ float psum[4][64];
  const int i0 = blockIdx.x * 64, o0 = blockIdx.y * 64;
  const int tc = threadIdx.x & 63, tr = threadIdx.x >> 6;
  float bs = 0.f;
  #pragma unroll
  for (int rr = 0; rr < 64; rr += 4) {
    f32x4 v = *(const f32x4*)&cc[((size_t)(i0 + rr + tr) * O + (o0 + tc)) * 4];
    t1[rr + tr][tc] = f2bf(v[1] - 3.f * v[3]);
    t2[rr + tr][tc] = f2bf(2.f * v[2]);
    t3[rr + tr][tc] = f2bf(4.f * v[3]);
    bs += v[0] - v[2];
  }
  psum[tr][tc] = bs;
  __syncthreads();
  const size_t plane = (size_t)O * I;
  #pragma unroll
  for (int rr = 0; rr < 64; rr += 4) {
    size_t ob = (size_t)(o0 + rr + tr) * I + i0 + tc;
    outp[ob]             = t1[tc][rr + tr];
    outp[ob + plane]     = t2[tc][rr + tr];
    outp[ob + 2 * plane] = t3[tc][rr + tr];
  }
  if (tr == 0)
    partial[(size_t)blockIdx.x * O + o0 + tc] =
        psum[0][tc] + psum[1][tc] + psum[2][tc] + psum[3][tc];
}

// deterministic finish: bias[o] = sum_k partial[k][o]
__global__ void bias_finish(const float* __restrict__ partial, float* __restrict__ bias,
                            int nblk, int O) {
  const int o = blockIdx.x * 256 + threadIdx.x;
  float s = 0.f;
  for (int k = 0; k < nblk; ++k) s += partial[(size_t)k * O + o];
  bias[o] = s;
}

__global__ void zero_pad_rows(unsigned short* __restrict__ p) {
  const size_t idx = ((size_t)blockIdx.x * 256 + threadIdx.x) * 4;
  u16x4 z = {0, 0, 0, 0};
  *(u16x4*)&p[(size_t)TOK * CH + idx] = z;
}

// ---------------- 128x128x32 bf16 MFMA GEMM, 1-ahead prefetch pipeline --------------
// A bf16 [TOKP][Ktot] row-major; BT bf16 [Nn][Ktot]. 256 thr, 2x2 waves.
// EPI: 0 -> bf16 C[row][Nn] ; 1 -> fp32 acc+bias+resid (0 on pad rows)
template <int EPI>
__global__ __launch_bounds__(256)
void gemm_kernel(const unsigned short* __restrict__ A,
                 const unsigned short* __restrict__ BT,
                 const int Ktot, const int Nn,
                 const float* __restrict__ bias,
                 const float* __restrict__ resid,
                 void* __restrict__ Cout) {
  __shared__ __align__(16) unsigned short As[2][128 * 32];
  __shared__ __align__(16) unsigned short Bs[2][128 * 32];
  const int t = threadIdx.x;
  const int lane = t & 63;
  const int wid = t >> 6;
  const int wm = wid >> 1, wn = wid & 1;
  const int bm = blockIdx.x * 128;
  const int bn = blockIdx.y * 128;
  const int srow = t >> 2;          // staging row within 64-row half
  const int scol = (t & 3) * 8;     // staging col (bf16)
  const int nkt = Ktot >> 5;
  f32x4 acc[4][4] = {};

  auto stage = [&](int buf, int kt) {
    const int kk = kt << 5;
    char* lb = (char*)&Bs[buf][0] + (wid << 10);
    async_copy16(lb,        &BT[(size_t)(bn + srow) * Ktot + kk + scol]);
    async_copy16(lb + 4096, &BT[(size_t)(bn + 64 + srow) * Ktot + kk + scol]);
    char* la = (char*)&As[buf][0] + (wid << 10);
    async_copy16(la,        &A[(size_t)(bm + srow) * Ktot + kk + scol]);
    async_copy16(la + 4096, &A[(size_t)(bm + 64 + srow) * Ktot + kk + scol]);
  };

  int cur = 0;
  stage(0, 0);
  for (int kt = 0; kt < nkt; ++kt) {
    if (kt + 1 < nkt) {
      stage(cur ^ 1, kt + 1);                       // issue next tile's loads first
      asm volatile("s_waitcnt vmcnt(4)" ::: "memory");   // cur tile's 4 loads done
    } else {
      asm volatile("s_waitcnt vmcnt(0)" ::: "memory");
    }
    __builtin_amdgcn_s_barrier();                   // cur staged by all waves
    __builtin_amdgcn_sched_barrier(0);
    bf16x8 af[4], bfr[4];
    const int frow = lane & 15;
    const int fk = (lane >> 4) * 8;
    #pragma unroll
    for (int m = 0; m < 4; ++m)
      af[m] = *(const bf16x8*)&As[cur][(wm * 64 + m * 16 + frow) * 32 + fk];
    #pragma unroll
    for (int n = 0; n < 4; ++n)
      bfr[n] = *(const bf16x8*)&Bs[cur][(wn * 64 + n * 16 + frow) * 32 + fk];
    #pragma unroll
    for (int m = 0; m < 4; ++m)
      #pragma unroll
      for (int n = 0; n < 4; ++n)
        acc[m][n] = __builtin_amdgcn_mfma_f32_16x16x32_bf16(af[m], bfr[n], acc[m][n], 0, 0, 0);
    __builtin_amdgcn_s_barrier();                   // reads done before next overwrite
    cur ^= 1;
  }
  // epilogue: C/D frag layout col=lane&15, row=4*(lane>>4)+r  [verified m89]
  #pragma unroll
  for (int m = 0; m < 4; ++m) {
    #pragma unroll
    for (int n = 0; n < 4; ++n) {
      #pragma unroll
      for (int r = 0; r < 4; ++r) {
        const int row = bm + wm * 64 + m * 16 + (lane >> 4) * 4 + r;
        const int col = bn + wn * 64 + n * 16 + (lane & 15);
        const float v = acc[m][n][r];
        if (EPI == 0) {
          ((unsigned short*)Cout)[(size_t)row * Nn + col] = f2bf(v);
        } else {
          float o = 0.f;
          if (row < TOK) o = v + bias[col] + resid[(size_t)row * Nn + col];
          ((float*)Cout)[(size_t)row * Nn + col] = o;
        }
      }
    }
  }
}

// ---------------- fused ChebyKAN GEMM: 128x64 tile, 4x1 waves, BK=32 ----------------
// A bf16 [TOKP][Ktot] holds t (or u); powers t^2,t^3 expanded in registers per wave
// (each row owned by exactly one wave -> no duplicate expansion).
// BT bf16 power-major planes [3][Nn][Ktot].
// LDS: As dbuf 16 KB + Bs dbuf 24 KB = 40 KB -> 4 blocks/CU.
// EPI: 0 -> bf16 fast_tanh(acc+bias) -> C[row][Nn]
//      1 -> fp32 acc+bias+resid, store rows<TOK only (d_out)
template <int EPI>
__global__ __launch_bounds__(256, 4)
void cheb_gemm(const unsigned short* __restrict__ A,
               const unsigned short* __restrict__ BT,
               const int Ktot, const int Nn,
               const float* __restrict__ bias,
               const float* __restrict__ resid,
               void* __restrict__ Cout) {
  __shared__ __align__(16) unsigned short As[2][128 * 32];      // 16 KB
  __shared__ __align__(16) unsigned short Bs[2][3 * 64 * 32];   // 24 KB
  const int t = threadIdx.x, lane = t & 63, wid = t >> 6;
  const int bm = blockIdx.x * 128, bn = blockIdx.y * 64;
  const int srow = t >> 2, scol = (t & 3) * 8;
  const int nkt = Ktot >> 5;
  f32x4 acc[2][4] = {};

  auto stage = [&](int buf, int kt) {
    const int kk = kt << 5;
    char* la = (char*)&As[buf][0] + (wid << 10);
    async_copy16(la,        &A[(size_t)(bm + srow) * Ktot + kk + scol]);
    async_copy16(la + 4096, &A[(size_t)(bm + 64 + srow) * Ktot + kk + scol]);
    char* lb = (char*)&Bs[buf][0] + (wid << 10);
    #pragma unroll
    for (int p = 0; p < 3; ++p)
      async_copy16(lb + p * 4096, &BT[((size_t)p * Nn + bn + srow) * Ktot + kk + scol]);
  };

  int cur = 0;
  stage(0, 0);                                       // 5 loads/wave in flight
  for (int kt = 0; kt < nkt; ++kt) {
    if (kt + 1 < nkt) {
      stage(cur ^ 1, kt + 1);                        // +5 -> 10 outstanding
      asm volatile("s_waitcnt vmcnt(5)" ::: "memory");    // cur tile's 5 done
    } else {
      asm volatile("s_waitcnt vmcnt(0)" ::: "memory");
    }
    __builtin_amdgcn_s_barrier();
    __builtin_amdgcn_sched_barrier(0);
    const int frow = lane & 15, fk = (lane >> 4) * 8;
    bf16x8 a1[2], a2[2], a3[2];
    #pragma unroll
    for (int m = 0; m < 2; ++m)
      a1[m] = *(const bf16x8*)&As[cur][(wid * 32 + m * 16 + frow) * 32 + fk];
    // in-register power expansion (bf16 truncation; rel err ~2^-9, within threshold)
    #pragma unroll
    for (int m = 0; m < 2; ++m) {
      const unsigned int* w = (const unsigned int*)&a1[m];
      unsigned int sq[4], cu[4];
      #pragma unroll
      for (int j = 0; j < 4; ++j) {
        const unsigned int u = w[j];
        const float lo = __builtin_bit_cast(float, u << 16);
        const float hi = __builtin_bit_cast(float, u & 0xffff0000u);
        const float lo2 = lo * lo, hi2 = hi * hi;
        const float lo3 = lo2 * lo, hi3 = hi2 * hi;
        sq[j] = (__builtin_bit_cast(unsigned int, hi2) & 0xffff0000u) |
                (__builtin_bit_cast(unsigned int, lo2) >> 16);
        cu[j] = (__builtin_bit_cast(unsigned int, hi3) & 0xffff0000u) |
                (__builtin_bit_cast(unsigned int, lo3) >> 16);
      }
      a2[m] = *(const bf16x8*)sq;
      a3[m] = *(const bf16x8*)cu;
    }
    #pragma unroll
    for (int p = 0; p < 3; ++p) {
      bf16x8 br[4];
      #pragma unroll
      for (int n = 0; n < 4; ++n)
        br[n] = *(const bf16x8*)&Bs[cur][(p * 64 + n * 16 + frow) * 32 + fk];
      #pragma unroll
      for (int m = 0; m < 2; ++m) {
        const bf16x8 a = (p == 0) ? a1[m] : (p == 1) ? a2[m] : a3[m];
        #pragma unroll
        for (int n = 0; n < 4; ++n)
          acc[m][n] = __builtin_amdgcn_mfma_f32_16x16x32_bf16(a, br[n], acc[m][n], 0, 0, 0);
      }
    }
    __builtin_amdgcn_s_barrier();
    cur ^= 1;
  }
  #pragma unroll
  for (int m = 0; m < 2; ++m) {
    #pragma unroll
    for (int n = 0; n < 4; ++n) {
      #pragma unroll
      for (int r = 0; r < 4; ++r) {
        const int row = bm + wid * 32 + m * 16 + (lane >> 4) * 4 + r;
        const int col = bn + n * 16 + (lane & 15);
        const float v = acc[m][n][r];
        if (EPI == 0) {
          ((unsigned short*)Cout)[(size_t)row * Nn + col] = f2bf(fast_tanh(v + bias[col]));
        } else {
          if (row < TOK)
            ((float*)Cout)[(size_t)row * Nn + col] = v + bias[col] + resid[(size_t)row * Nn + col];
        }
      }
    }
  }
}

// ---------------- attention: one block per (b,head), 4 waves ------------------------
__global__ __launch_bounds__(256)
void attn_kernel(const unsigned short* __restrict__ qkv, unsigned short* __restrict__ aout) {
  constexpr int VSTR = 232;   // padded col stride (keys), 464B rows: ~2-way banks, 16B aligned
  __shared__ __align__(16) unsigned short Vlds[64 * VSTR];      // V^T [d][key]
  __shared__ __align__(16) unsigned short Plds[4][16 * VSTR];   // per-wave P [q][key]
  const int bh = blockIdx.x;
  const int b = bh / NHEADS, hh = bh - b * NHEADS;
  const int t = threadIdx.x, lane = t & 63, wid = t >> 6;
  const size_t base = (size_t)b * SEQ * H3;
  // stage V^T (zero pad keys >= SEQ)
  const int part = t & 7, key0 = t >> 3;
  for (int it = 0; it < 7; ++it) {
    const int key = key0 + it * 32;
    u32x4 raw = {0, 0, 0, 0};
    if (key < SEQ)
      raw = *(const u32x4*)&qkv[base + (size_t)key * H3 + 2 * CH + hh * HD + part * 8];
    const unsigned short* us = (const unsigned short*)&raw;
    #pragma unroll
    for (int e = 0; e < 8; ++e)
      Vlds[(part * 8 + e) * VSTR + key] = us[e];
  }
  // zero P pad columns [208,224)
  for (int idx = t; idx < 4 * 16 * 16; idx += 256) {
    const int buf = idx >> 8, rr = (idx >> 4) & 15, ccc = idx & 15;
    Plds[buf][rr * VSTR + 208 + ccc] = 0;
  }
  __syncthreads();

  for (int qt = wid; qt < 13; qt += 4) {
    const int qrow = qt * 16 + (lane & 15);              // may be >=SEQ; stores guarded
    const size_t qbase = base + (size_t)qrow * H3 + hh * HD + (lane >> 4) * 8;
    const bf16x8 qf0 = *(const bf16x8*)&qkv[qbase];
    const bf16x8 qf1 = *(const bf16x8*)&qkv[qbase + 32];
    float sv[13][4];
    #pragma unroll
    for (int ktile = 0; ktile < 13; ++ktile) {
      const int keyc = ktile * 16 + (lane & 15);
      const size_t kbase = base + (size_t)keyc * H3 + CH + hh * HD + (lane >> 4) * 8;
      const bf16x8 kf0 = *(const bf16x8*)&qkv[kbase];
      const bf16x8 kf1 = *(const bf16x8*)&qkv[kbase + 32];
      f32x4 s = {0.f, 0.f, 0.f, 0.f};
      s = __builtin_amdgcn_mfma_f32_16x16x32_bf16(qf0, kf0, s, 0, 0, 0);
      s = __builtin_amdgcn_mfma_f32_16x16x32_bf16(qf1, kf1, s, 0, 0, 0);
      const bool valid = keyc < SEQ;
      #pragma unroll
      for (int r = 0; r < 4; ++r)
        sv[ktile][r] = valid ? s[r] * 0.125f : -INFINITY;
    }
    // softmax over keys: rows live across the 16 lanes of each quarter-wave
    float rsum[4];
    #pragma unroll
    for (int r = 0; r < 4; ++r) {
      float mx = -INFINITY;
      #pragma unroll
      for (int kt2 = 0; kt2 < 13; ++kt2) mx = fmaxf(mx, sv[kt2][r]);
      #pragma unroll
      for (int off = 1; off < 16; off <<= 1) mx = fmaxf(mx, __shfl_xor(mx, off));
      float sum = 0.f;
      #pragma unroll
      for (int kt2 = 0; kt2 < 13; ++kt2) {
        const float p = __expf(sv[kt2][r] - mx);
        sv[kt2][r] = p;
        sum += p;
      }
      #pragma unroll
      for (int off = 1; off < 16; off <<= 1) sum += __shfl_xor(sum, off);
      rsum[r] = sum;
    }
    // P -> LDS (transpose lanes->rows for the PV A-operand)
    const int g4 = (lane >> 4) * 4;
    #pragma unroll
    for (int kt2 = 0; kt2 < 13; ++kt2)
      #pragma unroll
      for (int r = 0; r < 4; ++r)
        Plds[wid][(g4 + r) * VSTR + kt2 * 16 + (lane & 15)] = f2bf(sv[kt2][r]);
    asm volatile("s_waitcnt lgkmcnt(0)" ::: "memory");   // same-wave ds_write -> ds_read
    // O = P @ V
    f32x4 oacc[4] = {};
    #pragma unroll
    for (int ks = 0; ks < 7; ++ks) {
      const bf16x8 pf = *(const bf16x8*)&Plds[wid][(lane & 15) * VSTR + ks * 32 + (lane >> 4) * 8];
      #pragma unroll
      for (int n = 0; n < 4; ++n) {
        const bf16x8 vf = *(const bf16x8*)&Vlds[(n * 16 + (lane & 15)) * VSTR + ks * 32 + (lane >> 4) * 8];
        oacc[n] = __builtin_amdgcn_mfma_f32_16x16x32_bf16(pf, vf, oacc[n], 0, 0, 0);
      }
    }
    #pragma unroll
    for (int n = 0; n < 4; ++n)
      #pragma unroll
      for (int r = 0; r < 4; ++r) {
        const int q = qt * 16 + g4 + r;
        if (q < SEQ) {
          const float val = oacc[n][r] / rsum[r];
          aout[(size_t)(b * SEQ + q) * CH + hh * HD + n * 16 + (lane & 15)] = f2bf(val);
        }
      }
  }
}

extern "C" void kernel_launch(void* const* d_in, const int* in_sizes, int n_in,
                              void* d_out, int out_size, void* d_ws, size_t ws_size,
                              hipStream_t stream) {
  const float* x      = (const float*)d_in[0];
  const float* g1     = (const float*)d_in[1];
  const float* b1     = (const float*)d_in[2];
  const float* w_qkv  = (const float*)d_in[3];
  const float* w_proj = (const float*)d_in[4];
  const float* b_proj = (const float*)d_in[5];
  const float* g2     = (const float*)d_in[6];
  const float* b2     = (const float*)d_in[7];
  const float* c1     = (const float*)d_in[8];
  const float* c2     = (const float*)d_in[9];

  // ---- workspace (no aliasing; peak ~151 MB) ----
  char* ws = (char*)d_ws;
  size_t off = 0;
  auto alloc = [&](size_t bytes) { size_t o = off; off += (bytes + 255) & ~(size_t)255; return o; };
  unsigned short* h      = (unsigned short*)(ws + alloc((size_t)TOKP * CH * 2));
  unsigned short* wqkvT  = (unsigned short*)(ws + alloc((size_t)H3 * CH * 2));
  unsigned short* wprojT = (unsigned short*)(ws + alloc((size_t)CH * CH * 2));
  unsigned short* c1T    = (unsigned short*)(ws + alloc((size_t)3 * HID * CH * 2));  // [3][HID][CH]
  unsigned short* c2T    = (unsigned short*)(ws + alloc((size_t)3 * CH * HID * 2));  // [3][CH][HID]
  float* bias1           = (float*)(ws + alloc((size_t)HID * 4));
  float* bias2           = (float*)(ws + alloc((size_t)CH * 4));
  float* part1           = (float*)(ws + alloc((size_t)(CH / 64) * HID * 4));
  float* part2           = (float*)(ws + alloc((size_t)(HID / 64) * CH * 4));
  unsigned short* qkvb   = (unsigned short*)(ws + alloc((size_t)TOKP * H3 * 2));
  unsigned short* aoutb  = (unsigned short*)(ws + alloc((size_t)TOKP * CH * 2));
  float* xmid            = (float*)(ws + alloc((size_t)TOKP * CH * 4));
  unsigned short* tb     = (unsigned short*)(ws + alloc((size_t)TOKP * CH * 2));     // t plane
  unsigned short* ub     = (unsigned short*)(ws + alloc((size_t)TOKP * HID * 2));    // u plane
  (void)ws_size; (void)in_sizes; (void)n_in; (void)out_size;

  // ---- per-launch weight prep (bf16, pre-transposed / cheby-folded) ----
  transpose_bf16<<<dim3(CH / 64, H3 / 64), 256, 0, stream>>>(w_qkv, wqkvT, CH, H3);
  transpose_bf16<<<dim3(CH / 64, CH / 64), 256, 0, stream>>>(w_proj, wprojT, CH, CH);
  cheb_combine<<<dim3(CH / 64, HID / 64), 256, 0, stream>>>(c1, c1T, part1, CH, HID);
  cheb_combine<<<dim3(HID / 64, CH / 64), 256, 0, stream>>>(c2, c2T, part2, HID, CH);
  bias_finish<<<dim3(HID / 256), 256, 0, stream>>>(part1, bias1, CH / 64, HID);
  bias_finish<<<dim3(CH / 256), 256, 0, stream>>>(part2, bias2, HID / 64, CH);
  zero_pad_rows<<<dim3(72), 256, 0, stream>>>(aoutb);

  // ---- main pipeline ----
  ln_kernel<0><<<dim3(TOKP / 4), 256, 0, stream>>>(x, g1, b1, h);
  gemm_kernel<0><<<dim3(TOKP / 128, H3 / 128), 256, 0, stream>>>(h, wqkvT, CH, H3,
                                                                 nullptr, nullptr, qkvb);
  attn_kernel<<<dim3(NBATCH * NHEADS), 256, 0, stream>>>(qkvb, aoutb);
  gemm_kernel<1><<<dim3(TOKP / 128, CH / 128), 256, 0, stream>>>(aoutb, wprojT, CH, CH,
                                                                 b_proj, x, xmid);
  ln_kernel<1><<<dim3(TOKP / 4), 256, 0, stream>>>(xmid, g2, b2, tb);
  // cheby1: fused powers-of-t GEMM, K = 768; epilogue u = tanh(acc+bias1), bf16
  cheb_gemm<0><<<dim3(TOKP / 128, HID / 64), 256, 0, stream>>>(tb, c1T, CH, HID,
                                                               bias1, nullptr, ub);
  // cheby2: fused powers-of-u GEMM, K = 3072; epilogue fp32 +bias2+resid -> d_out
  cheb_gemm<1><<<dim3(TOKP / 128, CH / 64), 256, 0, stream>>>(ub, c2T, HID, CH,
                                                              bias2, xmid, (float*)d_out);
}